// Round 8
// baseline (1198.917 us; speedup 1.0000x reference)
//
#include <hip/hip_runtime.h>
#include <math.h>

// Batched exact Hungarian (Jonker-Volgenant). One wave per batch; lane l owns
// contiguous columns j = 4l..4l+3 (jj = 4l+k+1): lowest-jj tie-break ==
// prefer-left local tree then lowest-lane ballot == jnp.argmin first-occur.
//
// FINAL (round-21) = round-16 verbatim: CR init + lane-parallel Jacobi ARR
// (MAXR=12, stall 3) + register-mirror Dijkstra pop loop. Best verified
// config: kernel 1149us, absmax=0.
//
// Session floor model (measured, rounds 4-7):
//   wall = Npops x chain x per-dep-latency + init
//        ~ 900 pops x ~30 dep-ops x ~13ns/op + ~200us = ~1150us
//   - Npops minimized to the H(F) floor; auction fixed point F~15-20
//     (round 5: more ARR rounds / GS backstop -> zero phase-2 change).
//   - chain slimming regressed (round 6: off-chain ops are free, any added
//     on-chain op costs ~13ns; payload tree keeps pulls off-path).
//   - per-dep latency is intrinsic: DVFS probe (round 7: 224 filler blocks,
//     VALUBusy 18%) changed nothing; ILP across batches irrelevant since
//     batches own separate CUs (round 4: pairing 2/wave = 2.2x worse).
//
// Output dtype: harness reads d_out as float32; col4row stored as floats.

#define NB   32
#define NN   256
#define ND   4
#define NPT  4
#define INFV 1e9f
#define MAXR 12

#if __has_builtin(__builtin_amdgcn_sqrtf)
__device__ __forceinline__ float fast_sqrtf(float x) { return __builtin_amdgcn_sqrtf(x); }
#else
__device__ __forceinline__ float fast_sqrtf(float x) {
    float r; asm volatile("v_sqrt_f32 %0, %1" : "=v"(r) : "v"(x)); return r;
}
#endif

__device__ __forceinline__ float wave_min_bcast(float x) {
    // 64-lane min in 5 dependent steps (min3 ladder); fill=1e9 never wins.
    const int fill = __float_as_int(INFV);
    int a, c;
    a = __builtin_amdgcn_update_dpp(fill, __float_as_int(x), 0x111, 0xF, 0xF, false); // row_shr:1
    c = __builtin_amdgcn_update_dpp(fill, __float_as_int(x), 0x112, 0xF, 0xF, false); // row_shr:2
    x = fminf(x, fminf(__int_as_float(a), __int_as_float(c)));      // cover 3
    a = __builtin_amdgcn_update_dpp(fill, __float_as_int(x), 0x113, 0xF, 0xF, false); // row_shr:3
    c = __builtin_amdgcn_update_dpp(fill, __float_as_int(x), 0x116, 0xF, 0xF, false); // row_shr:6
    x = fminf(x, fminf(__int_as_float(a), __int_as_float(c)));      // cover 9
    a = __builtin_amdgcn_update_dpp(fill, __float_as_int(x), 0x117, 0xF, 0xF, false); // row_shr:7
    x = fminf(x, __int_as_float(a));                                // cover 16
    a = __builtin_amdgcn_update_dpp(fill, __float_as_int(x), 0x142, 0xF, 0xF, false); // row_bcast:15
    x = fminf(x, __int_as_float(a));
    a = __builtin_amdgcn_update_dpp(fill, __float_as_int(x), 0x143, 0xF, 0xF, false); // row_bcast:31
    x = fminf(x, __int_as_float(a));                                // lane63 = global
    return __int_as_float(__builtin_amdgcn_readlane(__float_as_int(x), 63));
}

__device__ __forceinline__ float readlane_f(float v, int lane) {
    return __int_as_float(__builtin_amdgcn_readlane(__float_as_int(v), lane));
}
__device__ __forceinline__ int readlane_i(int v, int lane) {
    return __builtin_amdgcn_readlane(v, lane);
}
// value-arg selects (NO pointers -> arrays stay SROA'd in VGPRs)
__device__ __forceinline__ float sel4f(float a0, float a1, float a2, float a3, int kk) {
    float u0 = (kk & 1) ? a1 : a0;
    float u1 = (kk & 1) ? a3 : a2;
    return (kk & 2) ? u1 : u0;
}
__device__ __forceinline__ int sel4i(int a0, int a1, int a2, int a3, int kk) {
    int u0 = (kk & 1) ? a1 : a0;
    int u1 = (kk & 1) ? a3 : a2;
    return (kk & 2) ? u1 : u0;
}

__global__ __launch_bounds__(64) void hungarian_kernel(
    const float* __restrict__ pred, const float* __restrict__ gt,
    float* __restrict__ out)
{
#pragma clang fp contract(off)
    const int b    = blockIdx.x;
    const int lane = threadIdx.x;

    const float* pb = pred + (size_t)b * NN * ND;
    const float* gb = gt   + (size_t)b * NN * ND;

    __shared__ int   claimed[NN];   // CR: row -> lowest claiming col jj
    __shared__ int   free_lds[NN];  // ARR: 1 = row free
    __shared__ int   list_lds[NN];  // ARR: free-row worklist (1-based rows)
    __shared__ int   mb_row[NN];    // ARR mailbox: winning row per column
    __shared__ float mb_u2[NN], mb_d[NN];
    __shared__ float mb_px[NN], mb_py[NN], mb_pz[NN], mb_pw[NN];
    __shared__ int   cnt_lds;

    // gt mirrors for owned columns 4l+k, pred-row mirrors for rows 4l+k
    float gx[NPT], gy[NPT], gz[NPT], gw[NPT];
    float qx[NPT], qy[NPT], qz[NPT], qw[NPT];
    #pragma unroll
    for (int k = 0; k < NPT; ++k) {
        float4 gv = ((const float4*)gb)[4 * lane + k];
        gx[k] = gv.x; gy[k] = gv.y; gz[k] = gv.z; gw[k] = gv.w;
        float4 pv = ((const float4*)pb)[4 * lane + k];
        qx[k] = pv.x; qy[k] = pv.y; qz[k] = pv.z; qw[k] = pv.w;
    }
    // column potentials + mirrors of the matched row's u and pred
    float v[NPT], ur[NPT], prx[NPT], pry[NPT], prz[NPT], prw[NPT];
    int pl[NPT];
    #pragma unroll
    for (int k = 0; k < NPT; ++k) {
        v[k] = 0.f; pl[k] = 0; ur[k] = 0.f;
        prx[k] = 0.f; pry[k] = 0.f; prz[k] = 0.f; prw[k] = 0.f;
    }
    const float FINF = __int_as_float(0x7f800000);   // +inf
    const float NINF = __int_as_float(0xff800000);   // -inf

    // ---------------- Phase 1: JV column reduction ----------------
    // colmin over rows with the SAME fp arithmetic as the pop-loop scan
    // (fma chain + fast sqrt) so reduced costs are exactly >= 0 and matched
    // edges are exactly 0. Strict < keeps FIRST (lowest row) argmin.
    float cmin[NPT];
    int   crow[NPT];
    #pragma unroll
    for (int k = 0; k < NPT; ++k) { cmin[k] = INFV; crow[k] = 0; }
    #pragma unroll 2
    for (int r = 0; r < NN; ++r) {
        const int kkr = r & 3, owr = r >> 2;
        float px = readlane_f(sel4f(qx[0], qx[1], qx[2], qx[3], kkr), owr);
        float py = readlane_f(sel4f(qy[0], qy[1], qy[2], qy[3], kkr), owr);
        float pz = readlane_f(sel4f(qz[0], qz[1], qz[2], qz[3], kkr), owr);
        float pw = readlane_f(sel4f(qw[0], qw[1], qw[2], qw[3], kkr), owr);
        #pragma unroll
        for (int k = 0; k < NPT; ++k) {
            float dx = px - gx[k], dy = py - gy[k];
            float dz = pz - gz[k], dw = pw - gw[k];
            float ss = dx * dx;
            ss = __builtin_fmaf(dy, dy, ss);
            ss = __builtin_fmaf(dz, dz, ss);
            ss = __builtin_fmaf(dw, dw, ss);
            float c = fast_sqrtf(ss);
            bool upd = c < cmin[k];
            crow[k] = upd ? (r + 1) : crow[k];
            cmin[k] = fminf(cmin[k], c);
        }
    }
    // claim argmin rows: lowest column jj wins (atomicMin on LDS)
    #pragma unroll
    for (int k = 0; k < NPT; ++k) claimed[4 * lane + k] = 0x7fffffff;
    __syncthreads();
    #pragma unroll
    for (int k = 0; k < NPT; ++k) atomicMin(&claimed[crow[k] - 1], 4 * lane + k + 1);
    __syncthreads();
    int rm[NPT];                         // row 4l+k matched?
    #pragma unroll
    for (int k = 0; k < NPT; ++k) rm[k] = (claimed[4 * lane + k] != 0x7fffffff);
    #pragma unroll
    for (int k = 0; k < NPT; ++k) {
        v[k]  = cmin[k];                 // feasible dual: cost - 0 - v >= 0 exactly
        pl[k] = (claimed[crow[k] - 1] == (4 * lane + k + 1)) ? crow[k] : 0;
    }
    // free-row table for ARR (LDS is the single source of truth during ARR)
    #pragma unroll
    for (int k = 0; k < NPT; ++k) free_lds[4 * lane + k] = rm[k] ? 0 : 1;
    // fetch pred coords of init-matched rows (per-lane global gather, once)
    #pragma unroll
    for (int k = 0; k < NPT; ++k) {
        int rr = pl[k];
        if (rr) {
            float4 pv = ((const float4*)pb)[rr - 1];
            prx[k] = pv.x; pry[k] = pv.y; prz[k] = pv.z; prw[k] = pv.w;
        }
    }

    // ---------------- Phase 1b: lane-parallel Jacobi ARR ----------------
    {
        int prevF = 0x7fffffff, stall = 0;
        for (int round = 0; round < MAXR; ++round) {
            if (lane == 0) cnt_lds = 0;
            __syncthreads();
            // build worklist + reset mailbox
            #pragma unroll
            for (int k = 0; k < NPT; ++k) {
                int r4 = 4 * lane + k;
                mb_row[r4] = 0x7fffffff;
                if (free_lds[r4]) {
                    int s = atomicAdd(&cnt_lds, 1);
                    list_lds[s] = r4 + 1;
                }
            }
            __syncthreads();
            const int F = cnt_lds;
            if (F == 0) break;
            if (F >= prevF) { if (++stall >= 3) break; } else stall = 0;
            prevF = F;

            // bid: one free row per lane (first 64 of the list this round)
            const bool act = lane < F;
            const int  row = act ? list_lds[lane] : 1;
            float4 pv = ((const float4*)pb)[row - 1];   // L1/L2-hot
            float m1 = INFV, m2 = INFV;
            int   j1c = 1;
            for (int ow = 0; ow < 64; ++ow) {
                #pragma unroll
                for (int kk = 0; kk < NPT; ++kk) {
                    float cgx = readlane_f(gx[kk], ow);
                    float cgy = readlane_f(gy[kk], ow);
                    float cgz = readlane_f(gz[kk], ow);
                    float cgw = readlane_f(gw[kk], ow);
                    float cvv = readlane_f(v[kk],  ow);
                    float dx = pv.x - cgx, dy = pv.y - cgy;
                    float dz = pv.z - cgz, dw = pv.w - cgw;
                    float ss = dx * dx;
                    ss = __builtin_fmaf(dy, dy, ss);
                    ss = __builtin_fmaf(dz, dz, ss);
                    ss = __builtin_fmaf(dw, dw, ss);
                    float c = fast_sqrtf(ss) - cvv;
                    bool lt = c < m1;
                    m2  = lt ? m1 : fminf(m2, c);
                    j1c = lt ? (4 * ow + kk + 1) : j1c;
                    m1  = lt ? c : m1;
                }
            }
            if (act) atomicMin(&mb_row[j1c - 1], row);
            __syncthreads();
            const bool won = act && (mb_row[j1c - 1] == row);
            if (won) {
                mb_u2[j1c - 1] = m2;
                mb_d [j1c - 1] = m2 - m1;    // >= 0
                mb_px[j1c - 1] = pv.x; mb_py[j1c - 1] = pv.y;
                mb_pz[j1c - 1] = pv.z; mb_pw[j1c - 1] = pv.w;
            }
            __syncthreads();
            // apply awards to the distributed column state
            #pragma unroll
            for (int k = 0; k < NPT; ++k) {
                const int c4 = 4 * lane + k;
                const int wr = mb_row[c4];
                if (wr != 0x7fffffff) {
                    const int old = pl[k];
                    if (old) free_lds[old - 1] = 1;    // dispossessed re-bids
                    free_lds[wr - 1] = 0;              // winner matched
                    pl[k]  = wr;
                    ur[k]  = mb_u2[c4];
                    v[k]  -= mb_d[c4];                  // only decreases
                    prx[k] = mb_px[c4]; pry[k] = mb_py[c4];
                    prz[k] = mb_pz[c4]; prw[k] = mb_pw[c4];
                }
            }
            // next-round top barrier orders these LDS writes vs reads
        }
    }
    __syncthreads();
    // rebuild free-row ballot masks for phase 2 (bit set = row free)
    int fr[NPT];
    #pragma unroll
    for (int k = 0; k < NPT; ++k) fr[k] = free_lds[4 * lane + k];
    const unsigned long long fm0 = __ballot(fr[0] != 0);
    const unsigned long long fm1 = __ballot(fr[1] != 0);
    const unsigned long long fm2 = __ballot(fr[2] != 0);
    const unsigned long long fm3 = __ballot(fr[3] != 0);

    // ---------------- Phase 2: shortest augmenting paths -------------------

    for (int i = 1; i <= NN; ++i) {
        const int im1 = i - 1;
        const unsigned long long mm = (im1 & 2) ? ((im1 & 1) ? fm3 : fm2)
                                                : ((im1 & 1) ? fm1 : fm0);
        if (!((mm >> (im1 >> 2)) & 1ull)) continue;   // row matched (CR/ARR)

        // row-start: pull pred row i from q-mirrors (wave-uniform owner)
        const int kki = im1 & 3, owi = im1 >> 2;
        float4 pr0;
        pr0.x = readlane_f(sel4f(qx[0], qx[1], qx[2], qx[3], kki), owi);
        pr0.y = readlane_f(sel4f(qy[0], qy[1], qy[2], qy[3], kki), owi);
        pr0.z = readlane_f(sel4f(qz[0], qz[1], qz[2], qz[3], kki), owi);
        pr0.w = readlane_f(sel4f(qw[0], qw[1], qw[2], qw[3], kki), owi);
        float4 pr = pr0;

        int codes[NPT];                    // (jj | pl<<12), constant per row
        #pragma unroll
        for (int k = 0; k < NPT; ++k) codes[k] = (4 * lane + k + 1) | (pl[k] << 12);
        float minv[NPT], vm[NPT], ucol[NPT], mcol[NPT];
        int   wayr[NPT];
        #pragma unroll
        for (int k = 0; k < NPT; ++k) {
            minv[k] = INFV; vm[k] = v[k]; ucol[k] = 0.f; mcol[k] = 0.f; wayr[k] = 0;
        }
        float u_i = 0.f;                          // running sum of deltas == ref u[i]
        int   j1  = 0;
        float ui  = 0.f;                          // u[p[j1]] row-start value
        int   i0n = i;

        for (int it = 0; it < NN + 2; ++it) {
            // branchless mark: jm1=-1 on first iter matches no lane
            const int   jm1 = j1 - 1;             // wave-uniform
            const float bu  = ui - u_i;
            #pragma unroll
            for (int k = 0; k < NPT; ++k) {
                bool hit = (4 * lane + k) == jm1;
                vm[k]   = hit ? NINF : vm[k];     // freezes wayr; cur=+inf
                minv[k] = hit ? FINF : minv[k];   // masks argmin
                ucol[k] = hit ? bu   : ucol[k];   // u_new = ucol + u_i_end
                mcol[k] = hit ? u_i  : mcol[k];   // v_new = (v - u_i_end) + mcol
            }
            // scan owned columns; fma ss + fast sqrt (decisions only)
            #pragma unroll
            for (int k = 0; k < NPT; ++k) {
                float dx = pr.x - gx[k], dy = pr.y - gy[k];
                float dz = pr.z - gz[k], dw = pr.w - gw[k];
                float ss = dx * dx;
                ss = __builtin_fmaf(dy, dy, ss);
                ss = __builtin_fmaf(dz, dz, ss);
                ss = __builtin_fmaf(dw, dw, ss);
                float cur = (fast_sqrtf(ss) - ui) - vm[k];   // used: +inf
                bool upd = cur < minv[k];
                wayr[k] = upd ? j1 : wayr[k];
                minv[k] = fminf(minv[k], cur);
            }
            // 2-level tree argmin with payloads (strict <, prefer-left)
            bool s01 = minv[1] < minv[0];
            float v01 = s01 ? minv[1] : minv[0];
            int   c01 = s01 ? codes[1] : codes[0];
            float u01 = s01 ? ur[1] : ur[0];
            float x01 = s01 ? prx[1] : prx[0];
            float y01 = s01 ? pry[1] : pry[0];
            float z01 = s01 ? prz[1] : prz[0];
            float w01 = s01 ? prw[1] : prw[0];
            bool s23 = minv[3] < minv[2];
            float v23 = s23 ? minv[3] : minv[2];
            int   c23 = s23 ? codes[3] : codes[2];
            float u23 = s23 ? ur[3] : ur[2];
            float x23 = s23 ? prx[3] : prx[2];
            float y23 = s23 ? pry[3] : pry[2];
            float z23 = s23 ? prz[3] : prz[2];
            float w23 = s23 ? prw[3] : prw[2];
            bool sF  = v23 < v01;
            float best       = sF ? v23 : v01;
            int   code_local = sF ? c23 : c01;
            float usel = sF ? u23 : u01;
            float xsel = sF ? x23 : x01;
            float ysel = sF ? y23 : y01;
            float zsel = sF ? z23 : z01;
            float wsel = sF ? w23 : w01;
            // wave argmin: value min via DPP; owner = lowest lane at min
            const float gmin = wave_min_bcast(best);
            unsigned long long msk = __ballot(best == gmin);
            int owner = __ffsll(msk) - 1;
            int code  = readlane_i(code_local, owner);
            int j1n   = code & 0xFFF;
            i0n       = code >> 12;
            // minimal updates: minv -= delta (used stay +inf); u_i += delta
            const float delta = gmin;
            #pragma unroll
            for (int k = 0; k < NPT; ++k) minv[k] -= delta;
            u_i += delta;
            j1 = j1n;
            if (i0n == 0) break;                  // free column (updates done)
            // pull winner's mirrored values (no LDS)
            ui   = readlane_f(usel, owner);
            pr.x = readlane_f(xsel, owner);
            pr.y = readlane_f(ysel, owner);
            pr.z = readlane_f(zsel, owner);
            pr.w = readlane_f(wsel, owner);
        }

        // deferred write-back, register-only (used == minv pinned to +inf)
        #pragma unroll
        for (int k = 0; k < NPT; ++k) {
            bool used = (minv[k] == FINF);
            float un = ucol[k] + u_i;
            ur[k] = used ? un : ur[k];
            v[k]  = used ? ((v[k] - u_i) + mcol[k]) : v[k];
        }
        // augment walk, register-only: p[j] = p[way[j]] chain via readlane
        int j = j1;
        while (j != 0) {
            int kj = (j - 1) & 3, oj = (j - 1) >> 2;          // uniform
            int jp = readlane_i(sel4i(wayr[0], wayr[1], wayr[2], wayr[3], kj), oj);
            bool z = (jp == 0);
            int kp = z ? 0 : ((jp - 1) & 3);
            int op = z ? 0 : ((jp - 1) >> 2);
            int   val  = readlane_i(sel4i(pl[0], pl[1], pl[2], pl[3], kp), op);
            float unew = readlane_f(sel4f(ur[0], ur[1], ur[2], ur[3], kp), op);
            float pnx  = readlane_f(sel4f(prx[0], prx[1], prx[2], prx[3], kp), op);
            float pny  = readlane_f(sel4f(pry[0], pry[1], pry[2], pry[3], kp), op);
            float pnz  = readlane_f(sel4f(prz[0], prz[1], prz[2], prz[3], kp), op);
            float pnw  = readlane_f(sel4f(prw[0], prw[1], prw[2], prw[3], kp), op);
            val  = z ? i     : val;        // p[0] == i
            unew = z ? u_i   : unew;       // u[i] just finalized
            pnx  = z ? pr0.x : pnx;
            pny  = z ? pr0.y : pny;
            pnz  = z ? pr0.z : pnz;
            pnw  = z ? pr0.w : pnw;
            #pragma unroll
            for (int k = 0; k < NPT; ++k) {
                bool hit = (4 * lane + k) == (j - 1);
                pl[k]  = hit ? val  : pl[k];
                ur[k]  = hit ? unew : ur[k];
                prx[k] = hit ? pnx  : prx[k];
                pry[k] = hit ? pny  : pry[k];
                prz[k] = hit ? pnz  : prz[k];
                prw[k] = hit ? pnw  : prw[k];
            }
            j = jp;
        }
    }

    // outputs (float32): col4row[b][r-1] = j ; total_cost[b]
    // IEEE sqrtf here (cost threshold is loose; col4row must be exact).
    float tot = 0.f;
    #pragma unroll
    for (int k = 0; k < NPT; ++k) {
        int j = 4 * lane + k;
        int r = pl[k];                        // 1-based matched row
        out[b * NN + (r - 1)] = (float)j;
        float dx = prx[k] - gx[k], dy = pry[k] - gy[k];
        float dz = prz[k] - gz[k], dw = prw[k] - gw[k];
        tot += sqrtf(dx * dx + dy * dy + dz * dz + dw * dw);
    }
    for (int off = 32; off; off >>= 1) tot += __shfl_xor(tot, off);
    if (lane == 0) out[NB * NN + b] = tot;
}

extern "C" void kernel_launch(void* const* d_in, const int* in_sizes, int n_in,
                              void* d_out, int out_size, void* d_ws, size_t ws_size,
                              hipStream_t stream) {
    const float* pred = (const float*)d_in[0];
    const float* gt   = (const float*)d_in[1];
    float* out = (float*)d_out;
    hipLaunchKernelGGL(hungarian_kernel, dim3(NB), dim3(64), 0, stream,
                       pred, gt, out);
}